// Round 1
// baseline (453.255 us; speedup 1.0000x reference)
//
#include <hip/hip_runtime.h>

// raindrop_fuse: per-batch affine warp (bilinear, zeros padding) of N*K feature
// maps followed by max-reduction over the map axis.
//
// Shapes (from setup_inputs): x (40, 64, 100, 252) f32, pairwise_t_matrix
// (2,5,5,4,4) f32, record_len (2,) i32 = [5,3]. rm / time_diffs are UNUSED by
// the reference output. Output (2, 64, 100, 252) f32.

#define C_   64
#define H_   100
#define W_   252
#define L_   5
#define K_   5
#define CPT  8           // channels per thread: amortize coord math across c
#define SCALE 1.6f       // DOWNSAMPLE * VOXEL = 4 * 0.4

__global__ __launch_bounds__(256)
void raindrop_fuse_kernel(const float* __restrict__ x,
                          const float* __restrict__ T,      // (B, L, K, 4, 4)
                          const int*   __restrict__ record_len,
                          float* __restrict__ out)
{
    const int h   = blockIdx.x;        // 0..H-1
    const int cg  = blockIdx.y;        // 0..C/CPT-1
    const int b   = blockIdx.z;        // 0..B-1
    const int tid = threadIdx.x;

    __shared__ float th[L_ * K_][6];   // per-map affine coefficients
    __shared__ int   s_start, s_NK;

    if (tid == 0) {
        int start = 0;
        for (int i = 0; i < b; ++i) start += record_len[i];
        s_start = start * K_;
        s_NK    = record_len[b] * K_;
    }
    // Compute theta for all L*K entries (indices always valid); only the first
    // NK are consumed. M[i][j] picks T rows 0,1 and cols 0,1,3, times `mult`.
    if (tid < L_ * K_) {
        const int l = tid / K_, k = tid % K_;
        const float* t = T + (((size_t)(b * L_ + l) * K_ + k) << 4);
        th[tid][0] = t[0];                                   // *1
        th[tid][1] = t[1] * ((float)H_ / (float)W_);
        th[tid][2] = t[3] * (2.0f / (SCALE * (float)W_));
        th[tid][3] = t[4] * ((float)W_ / (float)H_);
        th[tid][4] = t[5];                                   // *1
        th[tid][5] = t[7] * (2.0f / (SCALE * (float)H_));
    }
    __syncthreads();

    const int w = tid;
    if (w >= W_) return;

    const float gx = (2.0f * (float)w + 1.0f) / (float)W_ - 1.0f;
    const float gy = (2.0f * (float)h + 1.0f) / (float)H_ - 1.0f;

    const int NK = s_NK;
    const int c0 = cg * CPT;
    const float* __restrict__ base =
        x + ((size_t)s_NK * 0) +                 // (no-op, keep ptr math simple)
        ((size_t)(s_start) * C_ + c0) * (size_t)(H_ * W_);

    float acc[CPT];
#pragma unroll
    for (int j = 0; j < CPT; ++j) acc[j] = -INFINITY;

    for (int n = 0; n < NK; ++n) {
        const float t00 = th[n][0], t01 = th[n][1], t02 = th[n][2];
        const float t10 = th[n][3], t11 = th[n][4], t12 = th[n][5];

        const float sx = t00 * gx + t01 * gy + t02;
        const float sy = t10 * gx + t11 * gy + t12;
        const float px = (sx + 1.0f) * (0.5f * (float)W_) - 0.5f;
        const float py = (sy + 1.0f) * (0.5f * (float)H_) - 0.5f;

        const float x0f = floorf(px), y0f = floorf(py);
        const float wx = px - x0f,   wy = py - y0f;
        const int x0 = (int)x0f, y0 = (int)y0f;
        const int x1 = x0 + 1,   y1 = y0 + 1;

        const bool vx0 = (x0 >= 0) & (x0 < W_);
        const bool vx1 = (x1 >= 0) & (x1 < W_);
        const bool vy0 = (y0 >= 0) & (y0 < H_);
        const bool vy1 = (y1 >= 0) & (y1 < H_);

        const float w00 = (1.0f - wx) * (1.0f - wy) * ((vx0 & vy0) ? 1.0f : 0.0f);
        const float w01 = wx          * (1.0f - wy) * ((vx1 & vy0) ? 1.0f : 0.0f);
        const float w10 = (1.0f - wx) * wy          * ((vx0 & vy1) ? 1.0f : 0.0f);
        const float w11 = wx          * wy          * ((vx1 & vy1) ? 1.0f : 0.0f);

        const int xc0 = min(max(x0, 0), W_ - 1);
        const int xc1 = min(max(x1, 0), W_ - 1);
        const int yc0 = min(max(y0, 0), H_ - 1);
        const int yc1 = min(max(y1, 0), H_ - 1);

        const int o00 = yc0 * W_ + xc0;
        const int o01 = yc0 * W_ + xc1;
        const int o10 = yc1 * W_ + xc0;
        const int o11 = yc1 * W_ + xc1;

        const float* __restrict__ p = base + (size_t)n * C_ * (size_t)(H_ * W_);
#pragma unroll
        for (int j = 0; j < CPT; ++j) {
            const float v = p[o00] * w00 + p[o01] * w01 +
                            p[o10] * w10 + p[o11] * w11;
            acc[j] = fmaxf(acc[j], v);
            p += H_ * W_;
        }
    }

    const size_t ob = ((size_t)(b * C_ + c0) * H_ + h) * (size_t)W_ + w;
#pragma unroll
    for (int j = 0; j < CPT; ++j)
        out[ob + (size_t)j * (H_ * W_)] = acc[j];
}

extern "C" void kernel_launch(void* const* d_in, const int* in_sizes, int n_in,
                              void* d_out, int out_size, void* d_ws, size_t ws_size,
                              hipStream_t stream) {
    const float* x          = (const float*)d_in[0];
    // d_in[1] = rm (unused), d_in[3] = time_diffs (unused)
    const float* T          = (const float*)d_in[2];
    const int*   record_len = (const int*)d_in[4];
    float*       out        = (float*)d_out;

    const int B = in_sizes[4];               // record_len element count (=2)
    dim3 grid(H_, C_ / CPT, B);
    raindrop_fuse_kernel<<<grid, 256, 0, stream>>>(x, T, record_len, out);
}

// Round 2
// 437.590 us; speedup vs baseline: 1.0358x; 1.0358x over previous
//
#include <hip/hip_runtime.h>

// raindrop_fuse: per-batch affine warp (bilinear, zeros padding) of N*K feature
// maps followed by max-reduction over the map axis.
//
// x (40, 64, 100, 252) f32, pairwise_t_matrix (2,5,5,4,4) f32,
// record_len (2,) i32 = [5,3]. rm / time_diffs UNUSED. Out (2,64,100,252) f32.
//
// R1 -> R2: L2 was thrashing (FETCH 560 MB vs 258 MB ideal). Blocks round-robin
// across XCDs by linear id; with h as blockIdx.x every XCD needed the whole
// ~35 MB active band in its 4 MB L2. Now blockIdx.x = channel-group so
// linear_id % 8 == cg % 8: each XCD exclusively owns an 8-channel slice
// (~5.4 MB working set, h-swept). CPT 8->4 doubles block count for latency
// hiding (VALUBusy was only 18%).

#define C_   64
#define H_   100
#define W_   252
#define L_   5
#define K_   5
#define CPT  4           // channels per thread
#define SCALE 1.6f       // DOWNSAMPLE * VOXEL = 4 * 0.4

__global__ __launch_bounds__(256)
void raindrop_fuse_kernel(const float* __restrict__ x,
                          const float* __restrict__ T,      // (B, L, K, 4, 4)
                          const int*   __restrict__ record_len,
                          float* __restrict__ out)
{
    const int cg  = blockIdx.x;        // 0..C/CPT-1  (x-major => id%8 == cg%8 => XCD owns channel slice)
    const int h   = blockIdx.y;        // 0..H-1
    const int b   = blockIdx.z;        // 0..B-1
    const int tid = threadIdx.x;

    __shared__ float th[L_ * K_][6];   // per-map affine coefficients
    __shared__ int   s_start, s_NK;

    if (tid == 0) {
        int start = 0;
        for (int i = 0; i < b; ++i) start += record_len[i];
        s_start = start * K_;
        s_NK    = record_len[b] * K_;
    }
    // theta for all L*K entries (always-valid indices); only first NK consumed.
    // M picks T rows 0,1 / cols 0,1,3, scaled by `mult`.
    if (tid < L_ * K_) {
        const int l = tid / K_, k = tid % K_;
        const float* t = T + (((size_t)(b * L_ + l) * K_ + k) << 4);
        th[tid][0] = t[0];                                   // *1
        th[tid][1] = t[1] * ((float)H_ / (float)W_);
        th[tid][2] = t[3] * (2.0f / (SCALE * (float)W_));
        th[tid][3] = t[4] * ((float)W_ / (float)H_);
        th[tid][4] = t[5];                                   // *1
        th[tid][5] = t[7] * (2.0f / (SCALE * (float)H_));
    }
    __syncthreads();

    const int w = tid;
    if (w >= W_) return;

    const float gx = (2.0f * (float)w + 1.0f) / (float)W_ - 1.0f;
    const float gy = (2.0f * (float)h + 1.0f) / (float)H_ - 1.0f;

    const int NK = s_NK;
    const int c0 = cg * CPT;
    const float* __restrict__ base =
        x + ((size_t)s_start * C_ + c0) * (size_t)(H_ * W_);

    float acc[CPT];
#pragma unroll
    for (int j = 0; j < CPT; ++j) acc[j] = -INFINITY;

    for (int n = 0; n < NK; ++n) {
        const float t00 = th[n][0], t01 = th[n][1], t02 = th[n][2];
        const float t10 = th[n][3], t11 = th[n][4], t12 = th[n][5];

        const float sx = t00 * gx + t01 * gy + t02;
        const float sy = t10 * gx + t11 * gy + t12;
        const float px = (sx + 1.0f) * (0.5f * (float)W_) - 0.5f;
        const float py = (sy + 1.0f) * (0.5f * (float)H_) - 0.5f;

        const float x0f = floorf(px), y0f = floorf(py);
        const float wx = px - x0f,   wy = py - y0f;
        const int x0 = (int)x0f, y0 = (int)y0f;
        const int x1 = x0 + 1,   y1 = y0 + 1;

        const bool vx0 = (x0 >= 0) & (x0 < W_);
        const bool vx1 = (x1 >= 0) & (x1 < W_);
        const bool vy0 = (y0 >= 0) & (y0 < H_);
        const bool vy1 = (y1 >= 0) & (y1 < H_);

        const float w00 = (1.0f - wx) * (1.0f - wy) * ((vx0 & vy0) ? 1.0f : 0.0f);
        const float w01 = wx          * (1.0f - wy) * ((vx1 & vy0) ? 1.0f : 0.0f);
        const float w10 = (1.0f - wx) * wy          * ((vx0 & vy1) ? 1.0f : 0.0f);
        const float w11 = wx          * wy          * ((vx1 & vy1) ? 1.0f : 0.0f);

        const int xc0 = min(max(x0, 0), W_ - 1);
        const int xc1 = min(max(x1, 0), W_ - 1);
        const int yc0 = min(max(y0, 0), H_ - 1);
        const int yc1 = min(max(y1, 0), H_ - 1);

        const int o00 = yc0 * W_ + xc0;
        const int o01 = yc0 * W_ + xc1;
        const int o10 = yc1 * W_ + xc0;
        const int o11 = yc1 * W_ + xc1;

        const float* __restrict__ p = base + (size_t)n * C_ * (size_t)(H_ * W_);
#pragma unroll
        for (int j = 0; j < CPT; ++j) {
            const float v = p[o00] * w00 + p[o01] * w01 +
                            p[o10] * w10 + p[o11] * w11;
            acc[j] = fmaxf(acc[j], v);
            p += H_ * W_;
        }
    }

    const size_t ob = ((size_t)(b * C_ + c0) * H_ + h) * (size_t)W_ + w;
#pragma unroll
    for (int j = 0; j < CPT; ++j)
        out[ob + (size_t)j * (H_ * W_)] = acc[j];
}

extern "C" void kernel_launch(void* const* d_in, const int* in_sizes, int n_in,
                              void* d_out, int out_size, void* d_ws, size_t ws_size,
                              hipStream_t stream) {
    const float* x          = (const float*)d_in[0];
    // d_in[1] = rm (unused), d_in[3] = time_diffs (unused)
    const float* T          = (const float*)d_in[2];
    const int*   record_len = (const int*)d_in[4];
    float*       out        = (float*)d_out;

    const int B = in_sizes[4];               // record_len element count (=2)
    dim3 grid(C_ / CPT, H_, B);
    raindrop_fuse_kernel<<<grid, 256, 0, stream>>>(x, T, record_len, out);
}

// Round 3
// 398.122 us; speedup vs baseline: 1.1385x; 1.0991x over previous
//
#include <hip/hip_runtime.h>

// raindrop_fuse: per-batch affine warp (bilinear, zeros padding) of N*K feature
// maps followed by max-reduction over the map axis.
//
// x (40, 64, 100, 252) f32, pairwise_t_matrix (2,5,5,4,4) f32,
// record_len (2,) i32 = [5,3]. rm / time_diffs UNUSED. Out (2,64,100,252) f32.
//
// R2 -> R3: R2 showed latency-bound (VALUBusy 27%, HBM 9.6%, VGPR=36 => no
// loads in flight across iterations; per-iter vmcnt(0) drain). Changes:
//  - Column-pair loads: corners (x0,x1) adjacent -> one 8B load per row per
//    channel (edge clamp handled by swapping the WEIGHTS once per n, so the
//    value path is branch-free). 16 -> 8 VMEM instr per n-iter.
//  - Explicit 2-deep pipeline (ping-pong register buffers): issue n+1's loads
//    before consuming n's, keeping ~16 loads in flight per wave.
// Keeps R2's XCD channel-slice swizzle (blockIdx.x = channel group).

#define C_   64
#define H_   100
#define W_   252
#define L_   5
#define K_   5
#define CPT  4           // channels per thread
#define SCALE 1.6f       // DOWNSAMPLE * VOXEL = 4 * 0.4
#define HW_  (H_ * W_)

// 8-byte value, 4-byte alignment: lets us load {p[o], p[o+1]} at arbitrary
// column parity in one global_load_dwordx2 (gfx9+ allows unaligned global).
typedef struct __attribute__((aligned(4))) { float x, y; } f2u;

__device__ __forceinline__ void stage_math(const float* __restrict__ thn,
                                           float gx, float gy,
                                           int& o0, int& o1,
                                           float& wA0, float& wB0,
                                           float& wA1, float& wB1)
{
    const float sx = thn[0] * gx + thn[1] * gy + thn[2];
    const float sy = thn[3] * gx + thn[4] * gy + thn[5];
    const float px = (sx + 1.0f) * (0.5f * (float)W_) - 0.5f;
    const float py = (sy + 1.0f) * (0.5f * (float)H_) - 0.5f;

    const float x0f = floorf(px), y0f = floorf(py);
    const float wx = px - x0f,   wy = py - y0f;
    const int x0 = (int)x0f, y0 = (int)y0f;
    const int x1 = x0 + 1,   y1 = y0 + 1;

    const bool vx0 = (x0 >= 0) & (x0 < W_);
    const bool vx1 = (x1 >= 0) & (x1 < W_);
    const bool vy0 = (y0 >= 0) & (y0 < H_);
    const bool vy1 = (y1 >= 0) & (y1 < H_);

    const float w00 = (1.0f - wx) * (1.0f - wy) * ((vx0 & vy0) ? 1.0f : 0.0f);
    const float w01 = wx          * (1.0f - wy) * ((vx1 & vy0) ? 1.0f : 0.0f);
    const float w10 = (1.0f - wx) * wy          * ((vx0 & vy1) ? 1.0f : 0.0f);
    const float w11 = wx          * wy          * ((vx1 & vy1) ? 1.0f : 0.0f);

    const int yc0 = min(max(y0, 0), H_ - 1);
    const int yc1 = min(max(y1, 0), H_ - 1);
    const int xp  = min(max(x0, 0), W_ - 2);   // pair base column

    o0 = yc0 * W_ + xp;
    o1 = yc1 * W_ + xp;

    // If x0 clamped (x0==-1 -> xp=0, or x0==W-1 -> xp=W-2), the pair elements
    // correspond to (x1-col, x0-col) swapped; the invalid one has weight 0,
    // so swapping the weights reproduces the exact reference arithmetic.
    const bool sel = (x0 == xp);
    wA0 = sel ? w00 : w01;  wB0 = sel ? w01 : w00;
    wA1 = sel ? w10 : w11;  wB1 = sel ? w11 : w10;
}

__device__ __forceinline__ void issue_loads(const float* __restrict__ p,
                                            int o0, int o1,
                                            f2u* r0, f2u* r1)
{
#pragma unroll
    for (int j = 0; j < CPT; ++j) {
        r0[j] = *reinterpret_cast<const f2u*>(p + o0);
        r1[j] = *reinterpret_cast<const f2u*>(p + o1);
        p += HW_;
    }
}

__global__ __launch_bounds__(256)
void raindrop_fuse_kernel(const float* __restrict__ x,
                          const float* __restrict__ T,      // (B, L, K, 4, 4)
                          const int*   __restrict__ record_len,
                          float* __restrict__ out)
{
    const int cg  = blockIdx.x;        // channel group (x-major => XCD owns slice)
    const int h   = blockIdx.y;
    const int b   = blockIdx.z;
    const int tid = threadIdx.x;

    __shared__ float th[L_ * K_][6];
    __shared__ int   s_start, s_NK;

    if (tid == 0) {
        int start = 0;
        for (int i = 0; i < b; ++i) start += record_len[i];
        s_start = start * K_;
        s_NK    = record_len[b] * K_;
    }
    if (tid < L_ * K_) {
        const int l = tid / K_, k = tid % K_;
        const float* t = T + (((size_t)(b * L_ + l) * K_ + k) << 4);
        th[tid][0] = t[0];
        th[tid][1] = t[1] * ((float)H_ / (float)W_);
        th[tid][2] = t[3] * (2.0f / (SCALE * (float)W_));
        th[tid][3] = t[4] * ((float)W_ / (float)H_);
        th[tid][4] = t[5];
        th[tid][5] = t[7] * (2.0f / (SCALE * (float)H_));
    }
    __syncthreads();

    const int w = tid;
    if (w >= W_) return;

    const float gx = (2.0f * (float)w + 1.0f) / (float)W_ - 1.0f;
    const float gy = (2.0f * (float)h + 1.0f) / (float)H_ - 1.0f;

    const int NK = s_NK;
    const int c0 = cg * CPT;
    const float* __restrict__ base =
        x + ((size_t)s_start * C_ + c0) * (size_t)HW_;

    float acc[CPT];
#pragma unroll
    for (int j = 0; j < CPT; ++j) acc[j] = -INFINITY;

    // --- 2-deep pipeline, ping-pong buffers A/B ---
    f2u  a0[CPT], a1[CPT], b0v[CPT], b1v[CPT];
    float awA0, awB0, awA1, awB1;
    float bwA0, bwB0, bwA1, bwB1;
    int o0, o1;

    stage_math(th[0], gx, gy, o0, o1, awA0, awB0, awA1, awB1);
    issue_loads(base, o0, o1, a0, a1);

    int n = 0;
    while (true) {
        // prefetch n+1 into B
        if (n + 1 < NK) {
            stage_math(th[n + 1], gx, gy, o0, o1, bwA0, bwB0, bwA1, bwB1);
            issue_loads(base + (size_t)(n + 1) * C_ * HW_, o0, o1, b0v, b1v);
        }
        // consume A
#pragma unroll
        for (int j = 0; j < CPT; ++j) {
            const float v = a0[j].x * awA0 + a0[j].y * awB0 +
                            a1[j].x * awA1 + a1[j].y * awB1;
            acc[j] = fmaxf(acc[j], v);
        }
        if (++n >= NK) break;

        // prefetch n+1 into A
        if (n + 1 < NK) {
            stage_math(th[n + 1], gx, gy, o0, o1, awA0, awB0, awA1, awB1);
            issue_loads(base + (size_t)(n + 1) * C_ * HW_, o0, o1, a0, a1);
        }
        // consume B
#pragma unroll
        for (int j = 0; j < CPT; ++j) {
            const float v = b0v[j].x * bwA0 + b0v[j].y * bwB0 +
                            b1v[j].x * bwA1 + b1v[j].y * bwB1;
            acc[j] = fmaxf(acc[j], v);
        }
        if (++n >= NK) break;
    }

    const size_t ob = ((size_t)(b * C_ + c0) * H_ + h) * (size_t)W_ + w;
#pragma unroll
    for (int j = 0; j < CPT; ++j)
        out[ob + (size_t)j * HW_] = acc[j];
}

extern "C" void kernel_launch(void* const* d_in, const int* in_sizes, int n_in,
                              void* d_out, int out_size, void* d_ws, size_t ws_size,
                              hipStream_t stream) {
    const float* x          = (const float*)d_in[0];
    // d_in[1] = rm (unused), d_in[3] = time_diffs (unused)
    const float* T          = (const float*)d_in[2];
    const int*   record_len = (const int*)d_in[4];
    float*       out        = (float*)d_out;

    const int B = in_sizes[4];               // record_len element count (=2)
    dim3 grid(C_ / CPT, H_, B);
    raindrop_fuse_kernel<<<grid, 256, 0, stream>>>(x, T, record_len, out);
}